// Round 7
// baseline (162.388 us; speedup 1.0000x reference)
//
#include <hip/hip_runtime.h>
#include <hip/hip_bf16.h>
#include <float.h>

#define EPSV 1e-6f
#define TGT_TILE 1024      // targets per block tile
#define SRC_TILE 1024      // src points per block
#define WAVES 8            // 512 threads
#define SPT 16             // src points per lane (1024 / 64)

typedef float f32x2 __attribute__((ext_vector_type(2)));

// Phase A: directed partial Hausdorff (squared), expansion form with packed
// fp32 math:
//   |s'-t|^2 = |s'|^2 + (|t|^2 - 2 s'.t),   s' = s + eps
// Tile stored SoA in LDS (xs[], ys[]) so one ds_read_b64 gives {x_{2i},x_{2i+1}}
// as an adjacent VGPR pair -> v_pk_fma_f32 operands. Per f32x2-slot (2 targets):
//   t2 = pk_fma(yy,yy, xx*xx)
//   per src: d = pk_fma(xx,nsx2, pk_fma(yy,nsy2,t2)); mm = min3(mm,d.x,d.y)
// Each wave's lane l holds the SAME 16 srcs; waves split the tile 8 ways.
// Cross-wave min via LDS, plain stores of (s2 + partial_min) to ws. No atomics.
__global__ __launch_bounds__(512, 2) void hausdorff_partial_kernel(
    const float* __restrict__ c1, const float* __restrict__ c2,
    float* __restrict__ ws, int L1, int L2, int STmax, int TTmax, int Lmax) {

    const int b   = blockIdx.y;
    const int B   = gridDim.y;
    const int dir = blockIdx.z;
    const int st  = blockIdx.x % STmax;
    const int tt  = blockIdx.x / STmax;

    const float* src; const float* tgt; int Lsrc, Ltgt;
    if (dir == 0) { src = c2 + (size_t)b * L2 * 2; tgt = c1 + (size_t)b * L1 * 2; Lsrc = L2; Ltgt = L1; }
    else          { src = c1 + (size_t)b * L1 * 2; tgt = c2 + (size_t)b * L2 * 2; Lsrc = L1; Ltgt = L2; }

    const int srcBase = st * SRC_TILE;
    const int tgtBase = tt * TGT_TILE;
    if (srcBase >= Lsrc || tgtBase >= Ltgt) return;   // uniform

    const int lane = threadIdx.x & 63;
    const int w    = threadIdx.x >> 6;

    __shared__ float xsf[TGT_TILE + 2];        // SoA target x (+pad)
    __shared__ float ysf[TGT_TILE + 2];        // SoA target y (+pad)
    __shared__ float red[WAVES][SRC_TILE];     // 32 KB
    __shared__ float s2s[SRC_TILE];            // 4 KB

    // This lane's 16 src points (identical across waves). Splats hoisted for pk.
    f32x2 nsx2[SPT], nsy2[SPT];
    float s2v[SPT];
    #pragma unroll
    for (int s = 0; s < SPT; ++s) {
        const int j = srcBase + s * 64 + lane;
        if (j < Lsrc) {
            float2 p = ((const float2*)src)[j];
            float sx = p.x + EPSV, sy = p.y + EPSV;
            float nx = -2.0f * sx, ny = -2.0f * sy;
            nsx2[s] = (f32x2){nx, nx};
            nsy2[s] = (f32x2){ny, ny};
            s2v[s]  = fmaf(sx, sx, sy * sy);
        } else {
            nsx2[s] = (f32x2){0.f, 0.f};
            nsy2[s] = (f32x2){0.f, 0.f};
            s2v[s]  = -FLT_MAX;   // phase B never reads j >= Lsrc
        }
    }

    // Stage this block's target tile, SoA.
    const int chunk = min(TGT_TILE, Ltgt - tgtBase);
    const float2* tg = (const float2*)tgt + tgtBase;
    for (int t = threadIdx.x; t < chunk; t += 512) {
        float2 p = tg[t];
        xsf[t] = p.x;
        ysf[t] = p.y;
    }
    if (threadIdx.x == 0 && (chunk & 1)) {
        xsf[chunk] = xsf[chunk - 1];   // dup pad (min-neutral)
        ysf[chunk] = ysf[chunk - 1];
    }
    __syncthreads();

    float mm[SPT];
    #pragma unroll
    for (int s = 0; s < SPT; ++s) mm[s] = FLT_MAX;

    const f32x2* xs2 = (const f32x2*)xsf;
    const f32x2* ys2 = (const f32x2*)ysf;

    const int P    = (chunk + 1) >> 1;       // f32x2 slots
    const int pbeg = (w * P) >> 3;
    const int pend = ((w + 1) * P) >> 3;

#define PROC(xx, yy) {                                                        \
        f32x2 t2 = __builtin_elementwise_fma((yy), (yy), (xx) * (xx));        \
        _Pragma("unroll")                                                     \
        for (int s = 0; s < SPT; ++s) {                                       \
            f32x2 d = __builtin_elementwise_fma((xx), nsx2[s],                \
                          __builtin_elementwise_fma((yy), nsy2[s], t2));      \
            mm[s] = fminf(fminf(mm[s], d.x), d.y);  /* -> v_min3_f32 */       \
        } }

    int i = pbeg;
    for (; i + 4 <= pend; i += 4) {
        f32x2 x0 = xs2[i + 0], y0 = ys2[i + 0];
        f32x2 x1 = xs2[i + 1], y1 = ys2[i + 1];
        f32x2 x2 = xs2[i + 2], y2 = ys2[i + 2];
        f32x2 x3 = xs2[i + 3], y3 = ys2[i + 3];
        PROC(x0, y0) PROC(x1, y1) PROC(x2, y2) PROC(x3, y3)
    }
    for (; i < pend; ++i) {
        f32x2 x0 = xs2[i], y0 = ys2[i];
        PROC(x0, y0)
    }
#undef PROC

    // publish per-wave partial mins (+ s2 once)
    #pragma unroll
    for (int s = 0; s < SPT; ++s)
        red[w][s * 64 + lane] = mm[s];
    if (w == 0) {
        #pragma unroll
        for (int s = 0; s < SPT; ++s)
            s2s[s * 64 + lane] = s2v[s];
    }
    __syncthreads();

    // combine across waves; each thread owns 2 srcs; plain stores
    for (int t = threadIdx.x; t < SRC_TILE; t += 512) {
        float m = red[0][t];
        #pragma unroll
        for (int ww = 1; ww < WAVES; ++ww)
            m = fminf(m, red[ww][t]);
        const size_t idx = ((size_t)((dir * B + b) * TTmax + tt)) * (size_t)Lmax
                           + (size_t)srcBase + t;
        ws[idx] = s2s[t] + m;
    }
}

// Phase B: per batch, min over tgt-tiles per src, max over srcs and both
// directions, sqrt, scale by resolution.
__global__ __launch_bounds__(512) void hausdorff_reduce_kernel(
    const float* __restrict__ ws, const float* __restrict__ res,
    float* __restrict__ out, int L1, int L2, int TTmax, int Lmax, int B) {

    const int b = blockIdx.x;
    float vmax = 0.0f;   // also serves as the >=0 clamp

    for (int dir = 0; dir < 2; ++dir) {
        const int Lsrc = (dir == 0) ? L2 : L1;
        const int Ltgt = (dir == 0) ? L1 : L2;
        const int nt   = (Ltgt + TGT_TILE - 1) / TGT_TILE;
        const float* base = ws + ((size_t)(dir * B + b) * TTmax) * (size_t)Lmax;
        for (int j = threadIdx.x; j < Lsrc; j += 512) {
            float m = base[j];
            for (int t = 1; t < nt; ++t)
                m = fminf(m, base[(size_t)t * Lmax + j]);
            vmax = fmaxf(vmax, m);
        }
    }

    for (int off = 32; off > 0; off >>= 1)
        vmax = fmaxf(vmax, __shfl_down(vmax, off));

    __shared__ float r[8];
    const int lane = threadIdx.x & 63, w = threadIdx.x >> 6;
    if (lane == 0) r[w] = vmax;
    __syncthreads();
    if (threadIdx.x == 0) {
        float m = r[0];
        #pragma unroll
        for (int i = 1; i < 8; ++i) m = fmaxf(m, r[i]);
        out[b] = sqrtf(fmaxf(m, 0.0f)) * res[b];
    }
}

extern "C" void kernel_launch(void* const* d_in, const int* in_sizes, int n_in,
                              void* d_out, int out_size, void* d_ws, size_t ws_size,
                              hipStream_t stream) {
    const float* c1  = (const float*)d_in[0];
    const float* c2  = (const float*)d_in[1];
    const float* res = (const float*)d_in[2];
    float* out = (float*)d_out;

    const int B  = in_sizes[2];
    const int L1 = in_sizes[0] / (B * 2);
    const int L2 = in_sizes[1] / (B * 2);

    float* ws = (float*)d_ws;

    const int Lmax  = max(L1, L2);
    const int STmax = (Lmax + SRC_TILE - 1) / SRC_TILE;
    const int TTmax = (Lmax + TGT_TILE - 1) / TGT_TILE;

    dim3 gridA(STmax * TTmax, B, 2);
    hipLaunchKernelGGL(hausdorff_partial_kernel, gridA, dim3(512), 0, stream,
                       c1, c2, ws, L1, L2, STmax, TTmax, Lmax);

    hipLaunchKernelGGL(hausdorff_reduce_kernel, dim3(B), dim3(512), 0, stream,
                       ws, res, out, L1, L2, TTmax, Lmax, B);
}

// Round 8
// 29.877 us; speedup vs baseline: 5.4352x; 5.4352x over previous
//
#include <hip/hip_runtime.h>
#include <hip/hip_bf16.h>
#include <float.h>

#define EPSV 1e-6f
#define TGT_TILE 2048      // targets per block tile (float2 = 16 KB LDS)
#define SRC_TILE 512       // src points per block
#define WAVES 8            // 512 threads
#define SPT 8              // src points per lane (512 / 64)

// Phase A: directed partial Hausdorff (squared), expansion form:
//   |s'-t|^2 = |s'|^2 + (|t|^2 - 2 s'.t),   s' = s + eps
// Block = (src_tile st, tgt_tile tt, batch b, dir). 512 threads = 8 waves.
// Every wave's lane l holds the SAME 8 srcs (scalar float arrays — NO
// ext_vector arrays, avoids scratch spill seen in round 7). Waves split the
// 1024 float4-slots (2 targets each) 8 ways; each broadcast ds_read_b128
// feeds 8 srcs: 44 VALU instr per 12-cyc DS read -> VALU-bound.
// Cross-wave min via LDS, plain stores of (s2 + partial_min) to ws. No atomics.
__global__ __launch_bounds__(512, 2) void hausdorff_partial_kernel(
    const float* __restrict__ c1, const float* __restrict__ c2,
    float* __restrict__ ws, int L1, int L2, int STmax, int TTmax, int Lmax) {

    const int b   = blockIdx.y;
    const int B   = gridDim.y;
    const int dir = blockIdx.z;
    const int st  = blockIdx.x % STmax;
    const int tt  = blockIdx.x / STmax;

    const float* src; const float* tgt; int Lsrc, Ltgt;
    if (dir == 0) { src = c2 + (size_t)b * L2 * 2; tgt = c1 + (size_t)b * L1 * 2; Lsrc = L2; Ltgt = L1; }
    else          { src = c1 + (size_t)b * L1 * 2; tgt = c2 + (size_t)b * L2 * 2; Lsrc = L1; Ltgt = L2; }

    const int srcBase = st * SRC_TILE;
    const int tgtBase = tt * TGT_TILE;
    if (srcBase >= Lsrc || tgtBase >= Ltgt) return;   // uniform

    const int lane = threadIdx.x & 63;
    const int w    = threadIdx.x >> 6;

    __shared__ float4 t_lds[TGT_TILE / 2];      // 16 KB, 2 targets per slot
    __shared__ float  red[WAVES][SRC_TILE];     // 16 KB
    __shared__ float  s2s[SRC_TILE];            // 2 KB

    // This lane's 8 src points (identical across waves), scalar registers.
    float nsx[SPT], nsy[SPT], s2v[SPT];
    #pragma unroll
    for (int s = 0; s < SPT; ++s) {
        const int j = srcBase + s * 64 + lane;
        if (j < Lsrc) {
            float2 p = ((const float2*)src)[j];
            float sx = p.x + EPSV, sy = p.y + EPSV;
            nsx[s] = -2.0f * sx;
            nsy[s] = -2.0f * sy;
            s2v[s] = fmaf(sx, sx, sy * sy);
        } else {
            nsx[s] = 0.f; nsy[s] = 0.f;
            s2v[s] = -FLT_MAX;   // phase B never reads j >= Lsrc
        }
    }

    // Stage this block's target tile (raw float2).
    const int chunk = min(TGT_TILE, Ltgt - tgtBase);
    const float2* tg = (const float2*)tgt + tgtBase;
    for (int t = threadIdx.x; t < chunk; t += 512) {
        ((float2*)t_lds)[t] = tg[t];
    }
    if (threadIdx.x == 0 && (chunk & 1)) {
        ((float2*)t_lds)[chunk] = tg[chunk - 1];   // dup pad (min-neutral)
    }
    __syncthreads();

    float mm[SPT];
    #pragma unroll
    for (int s = 0; s < SPT; ++s) mm[s] = FLT_MAX;

    const int P    = (chunk + 1) >> 1;       // float4 slots
    const int pbeg = (w * P) >> 3;
    const int pend = ((w + 1) * P) >> 3;

#define PROC(a) {                                                          \
        float t2a = fmaf((a).y, (a).y, (a).x * (a).x);                     \
        float t2b = fmaf((a).w, (a).w, (a).z * (a).z);                     \
        _Pragma("unroll")                                                  \
        for (int s = 0; s < SPT; ++s) {                                    \
            float da = fmaf((a).x, nsx[s], fmaf((a).y, nsy[s], t2a));      \
            float db = fmaf((a).z, nsx[s], fmaf((a).w, nsy[s], t2b));      \
            mm[s] = fminf(fminf(mm[s], da), db);  /* -> v_min3_f32 */      \
        } }

    int i = pbeg;
    for (; i + 4 <= pend; i += 4) {
        float4 a0 = t_lds[i + 0];
        float4 a1 = t_lds[i + 1];
        float4 a2 = t_lds[i + 2];
        float4 a3 = t_lds[i + 3];
        PROC(a0) PROC(a1) PROC(a2) PROC(a3)
    }
    for (; i < pend; ++i) {
        float4 a0 = t_lds[i];
        PROC(a0)
    }
#undef PROC

    // publish per-wave partial mins (+ s2 once)
    #pragma unroll
    for (int s = 0; s < SPT; ++s)
        red[w][s * 64 + lane] = mm[s];
    if (w == 0) {
        #pragma unroll
        for (int s = 0; s < SPT; ++s)
            s2s[s * 64 + lane] = s2v[s];
    }
    __syncthreads();

    // combine across waves; thread t owns src (srcBase + t); plain store
    const int t = threadIdx.x;
    float m = red[0][t];
    #pragma unroll
    for (int ww = 1; ww < WAVES; ++ww)
        m = fminf(m, red[ww][t]);
    const size_t idx = ((size_t)((dir * B + b) * TTmax + tt)) * (size_t)Lmax
                       + (size_t)srcBase + t;
    ws[idx] = s2s[t] + m;
}

// Phase B: per batch, min over tgt-tiles per src, max over srcs and both
// directions, sqrt, scale by resolution.
__global__ __launch_bounds__(512) void hausdorff_reduce_kernel(
    const float* __restrict__ ws, const float* __restrict__ res,
    float* __restrict__ out, int L1, int L2, int TTmax, int Lmax, int B) {

    const int b = blockIdx.x;
    float vmax = 0.0f;   // also serves as the >=0 clamp

    for (int dir = 0; dir < 2; ++dir) {
        const int Lsrc = (dir == 0) ? L2 : L1;
        const int Ltgt = (dir == 0) ? L1 : L2;
        const int nt   = (Ltgt + TGT_TILE - 1) / TGT_TILE;
        const float* base = ws + ((size_t)(dir * B + b) * TTmax) * (size_t)Lmax;
        for (int j = threadIdx.x; j < Lsrc; j += 512) {
            float m = base[j];
            for (int t = 1; t < nt; ++t)
                m = fminf(m, base[(size_t)t * Lmax + j]);
            vmax = fmaxf(vmax, m);
        }
    }

    for (int off = 32; off > 0; off >>= 1)
        vmax = fmaxf(vmax, __shfl_down(vmax, off));

    __shared__ float r[8];
    const int lane = threadIdx.x & 63, w = threadIdx.x >> 6;
    if (lane == 0) r[w] = vmax;
    __syncthreads();
    if (threadIdx.x == 0) {
        float m = r[0];
        #pragma unroll
        for (int i = 1; i < 8; ++i) m = fmaxf(m, r[i]);
        out[b] = sqrtf(fmaxf(m, 0.0f)) * res[b];
    }
}

extern "C" void kernel_launch(void* const* d_in, const int* in_sizes, int n_in,
                              void* d_out, int out_size, void* d_ws, size_t ws_size,
                              hipStream_t stream) {
    const float* c1  = (const float*)d_in[0];
    const float* c2  = (const float*)d_in[1];
    const float* res = (const float*)d_in[2];
    float* out = (float*)d_out;

    const int B  = in_sizes[2];
    const int L1 = in_sizes[0] / (B * 2);
    const int L2 = in_sizes[1] / (B * 2);

    float* ws = (float*)d_ws;

    const int Lmax  = max(L1, L2);
    const int STmax = (Lmax + SRC_TILE - 1) / SRC_TILE;
    const int TTmax = (Lmax + TGT_TILE - 1) / TGT_TILE;

    dim3 gridA(STmax * TTmax, B, 2);
    hipLaunchKernelGGL(hausdorff_partial_kernel, gridA, dim3(512), 0, stream,
                       c1, c2, ws, L1, L2, STmax, TTmax, Lmax);

    hipLaunchKernelGGL(hausdorff_reduce_kernel, dim3(B), dim3(512), 0, stream,
                       ws, res, out, L1, L2, TTmax, Lmax, B);
}